// Round 8
// baseline (130.418 us; speedup 1.0000x reference)
//
#include <hip/hip_runtime.h>
#include <hip/hip_bf16.h>
#include <stdint.h>

typedef __attribute__((ext_vector_type(8))) short bf16x8;
typedef __attribute__((ext_vector_type(4))) float f32x4;
typedef __attribute__((ext_vector_type(4))) unsigned int u32x4;

__device__ __forceinline__ float u2f(unsigned int u) {
  union { unsigned int i; float f; } c; c.i = u; return c.f;
}
__device__ __forceinline__ unsigned int f2b(float f) {
  union { float f; unsigned int i; } c; c.f = f;
  unsigned int x = c.i;
  return (x + 0x7fffu + ((x >> 16) & 1u)) >> 16;  // RNE to bf16
}

// ================= prep kernel (unchanged) =================
__global__ __launch_bounds__(256) void k_prep(
    const float* __restrict__ shape, const float* __restrict__ w_off,
    const float* __restrict__ x, const float* __restrict__ wd,
    char* __restrict__ desc, unsigned short* __restrict__ xt,
    unsigned short* __restrict__ wp) {
  __shared__ float tile[64][65];
  int bid = blockIdx.x;
  int t = threadIdx.x;
  if (bid < 576) {
    // ---- descriptors (16B): {u32 idx01 (two u16 pos idx), u32 idx23, u32 w01, u32 w23} ----
    int band = bid & 3;
    int rem = bid >> 2;                 // = b*36 + g*9 + kk
    int b = rem / 36, r2 = rem % 36, g = r2 / 9, kk = r2 % 9;
    int ky = kk / 3, kx = kk - ky * 3;
    int ocy = g * 18 + kk * 2;
    float wy[18], wx[18];
#pragma unroll
    for (int i = 0; i < 18; ++i) { wy[i] = w_off[ocy * 18 + i]; wx[i] = w_off[(ocy + 1) * 18 + i]; }
    const float* sp = shape + (size_t)b * 2 * 4096;
    char* dp = desc + (size_t)rem * 4096 * 16;
#pragma unroll
    for (int e = 0; e < 4; ++e) {
      int p = band * 1024 + t * 4 + e;
      int y = p >> 6, xx0 = p & 63;
      float dy = 0.f, dx = 0.f;
#pragma unroll
      for (int ic = 0; ic < 2; ++ic)
#pragma unroll
        for (int kyy = 0; kyy < 3; ++kyy) {
          int yy = y + kyy - 1;
          if (yy < 0 || yy > 63) continue;
#pragma unroll
          for (int kxx = 0; kxx < 3; ++kxx) {
            int xx = xx0 + kxx - 1;
            if (xx < 0 || xx > 63) continue;
            float sv = sp[ic * 4096 + yy * 64 + xx];
            dy += sv * wy[ic * 9 + kyy * 3 + kxx];
            dx += sv * wx[ic * 9 + kyy * 3 + kxx];
          }
        }
      float sy = dy + (float)(y + ky - 1);
      float sx = dx + (float)(xx0 + kx - 1);
      float fy = floorf(sy), fx = floorf(sx);
      float ly = sy - fy, lx = sx - fx;
      int y0 = (int)fy, x0 = (int)fx;
      float vy0 = (y0 >= 0 && y0 <= 63) ? 1.f : 0.f;
      float vy1 = (y0 >= -1 && y0 <= 62) ? 1.f : 0.f;
      float vx0 = (x0 >= 0 && x0 <= 63) ? 1.f : 0.f;
      float vx1 = (x0 >= -1 && x0 <= 62) ? 1.f : 0.f;
      float w00 = (1.f - ly) * (1.f - lx) * vy0 * vx0;
      float w01 = (1.f - ly) * lx * vy0 * vx1;
      float w10 = ly * (1.f - lx) * vy1 * vx0;
      float w11 = ly * lx * vy1 * vx1;
      unsigned int yc0 = (unsigned int)min(max(y0, 0), 63);
      unsigned int yc1 = (unsigned int)min(max(y0 + 1, 0), 63);
      unsigned int xc0 = (unsigned int)min(max(x0, 0), 63);
      unsigned int xc1 = (unsigned int)min(max(x0 + 1, 0), 63);
      u32x4 d;
      d[0] = (yc0 * 64 + xc0) | ((yc0 * 64 + xc1) << 16);
      d[1] = (yc1 * 64 + xc0) | ((yc1 * 64 + xc1) << 16);
      d[2] = f2b(w00) | (f2b(w01) << 16);
      d[3] = f2b(w10) | (f2b(w11) << 16);
      *(u32x4*)(dp + (size_t)p * 16) = d;
    }
  } else if (bid < 1600) {
    // ---- transpose ----
    int id = bid - 576;
    int b = id >> 8, ct = (id >> 6) & 3, pt = id & 63;
    int c0 = ct * 64, p0 = pt * 64;
#pragma unroll
    for (int i = 0; i < 4; ++i) {
      int row = (t >> 4) + i * 16;
      int seg = t & 15;
      float4 v = *(const float4*)&x[(size_t)(b * 256 + c0 + row) * 4096 + p0 + seg * 4];
      tile[row][seg * 4 + 0] = v.x;
      tile[row][seg * 4 + 1] = v.y;
      tile[row][seg * 4 + 2] = v.z;
      tile[row][seg * 4 + 3] = v.w;
    }
    __syncthreads();
    {
      int pl = t >> 2;
      int cs = (t & 3) * 16;
      unsigned int wbuf[8];
#pragma unroll
      for (int j = 0; j < 8; ++j)
        wbuf[j] = f2b(tile[cs + 2 * j][pl]) | (f2b(tile[cs + 2 * j + 1][pl]) << 16);
      unsigned short* dst = xt + (size_t)(b * 4096 + p0 + pl) * 256 + c0 + cs;
      *(u32x4*)(dst) = *(u32x4*)&wbuf[0];
      *(u32x4*)(dst + 8) = *(u32x4*)&wbuf[4];
    }
  } else {
    // ---- weight pack: wp[chunk=kk*4+g][m][c] = wd[m][g*64+c][kk] (linear rows) ----
    int id = (bid - 1600) * 256 + t;
    int m = id >> 8, ci = id & 255;
    int g = ci >> 6, c = ci & 63;
    const float* src = wd + (size_t)(m * 256 + ci) * 9;
    float v[9];
#pragma unroll
    for (int kk = 0; kk < 9; ++kk) v[kk] = src[kk];
#pragma unroll
    for (int kk = 0; kk < 9; ++kk)
      wp[(size_t)(kk * 4 + g) * 16384 + m * 64 + c] = (unsigned short)f2b(v[kk]);
  }
}

// ================= main fused kernel =================
// grid 1024: (pair = b,y,xh) x mb; 512 threads (8 waves), launch_bounds(512,6) -> 3 blocks/CU,
// 24 waves/CU in 3 independent barrier groups. Tile M=128 x N=32 per block.
// A: global->VGPR, ONE PHASE AHEAD (no vmem wait inside phase). B: LDS dbuf 2x4KB.
// Barrier = lgkmcnt(0)+s_barrier only. Corners 1 phase ahead, desc 2 ahead.
struct CSet { uint2 v0, v1, v2, v3; unsigned int w01, w23; };

#define DESC_LD(c, dv) do { \
    dv = *(const u32x4*)(descb + (size_t)(((c) & 3) * 9 + ((c) >> 2)) * 65536); \
  } while (0)

#define CORNERS(S, dv, cc) do { \
    unsigned int base_ = (unsigned int)(((cc) & 3) << 7) + cb8; \
    (S).v0 = *(const uint2*)(xtbB + (((dv)[0] & 0xffffu) << 9) + base_); \
    (S).v1 = *(const uint2*)(xtbB + (((dv)[0] >> 16) << 9) + base_); \
    (S).v2 = *(const uint2*)(xtbB + (((dv)[1] & 0xffffu) << 9) + base_); \
    (S).v3 = *(const uint2*)(xtbB + (((dv)[1] >> 16) << 9) + base_); \
    (S).w01 = (dv)[2]; \
    (S).w23 = (dv)[3]; \
  } while (0)

#define BLEND(S, bbuf) do { \
    float w0_ = u2f((S).w01 << 16), w1_ = u2f((S).w01 & 0xffff0000u); \
    float w2_ = u2f((S).w23 << 16), w3_ = u2f((S).w23 & 0xffff0000u); \
    uint2 o_; \
    { \
      float lo_ = w0_ * u2f((S).v0.x << 16) + w1_ * u2f((S).v1.x << 16) \
                + w2_ * u2f((S).v2.x << 16) + w3_ * u2f((S).v3.x << 16); \
      float hi_ = w0_ * u2f((S).v0.x & 0xffff0000u) + w1_ * u2f((S).v1.x & 0xffff0000u) \
                + w2_ * u2f((S).v2.x & 0xffff0000u) + w3_ * u2f((S).v3.x & 0xffff0000u); \
      o_.x = f2b(lo_) | (f2b(hi_) << 16); \
    } \
    { \
      float lo_ = w0_ * u2f((S).v0.y << 16) + w1_ * u2f((S).v1.y << 16) \
                + w2_ * u2f((S).v2.y << 16) + w3_ * u2f((S).v3.y << 16); \
      float hi_ = w0_ * u2f((S).v0.y & 0xffff0000u) + w1_ * u2f((S).v1.y & 0xffff0000u) \
                + w2_ * u2f((S).v2.y & 0xffff0000u) + w3_ * u2f((S).v3.y & 0xffff0000u); \
      o_.y = f2b(lo_) | (f2b(hi_) << 16); \
    } \
    *(uint2*)((bbuf) + bwr) = o_; \
  } while (0)

#define LOAD_A(c, F) do { \
    const unsigned short* ap_ = wpl + (size_t)(c) * 16384; \
    F##0 = *(const bf16x8*)(ap_); \
    F##1 = *(const bf16x8*)(ap_ + 32); \
  } while (0)

#define MFMA4(F, bbuf) do { \
    bf16x8 b0_ = *(const bf16x8*)((bbuf) + brow0 + (kq ^ swz)); \
    bf16x8 b1_ = *(const bf16x8*)((bbuf) + brow1 + (kq ^ swz)); \
    acc0 = __builtin_amdgcn_mfma_f32_16x16x32_bf16(F##0, b0_, acc0, 0, 0, 0); \
    acc1 = __builtin_amdgcn_mfma_f32_16x16x32_bf16(F##0, b1_, acc1, 0, 0, 0); \
    bf16x8 b2_ = *(const bf16x8*)((bbuf) + brow0 + ((64 + kq) ^ swz)); \
    bf16x8 b3_ = *(const bf16x8*)((bbuf) + brow1 + ((64 + kq) ^ swz)); \
    acc0 = __builtin_amdgcn_mfma_f32_16x16x32_bf16(F##1, b2_, acc0, 0, 0, 0); \
    acc1 = __builtin_amdgcn_mfma_f32_16x16x32_bf16(F##1, b3_, acc1, 0, 0, 0); \
  } while (0)

#define BAR() do { \
    asm volatile("s_waitcnt lgkmcnt(0)" ::: "memory"); \
    __builtin_amdgcn_s_barrier(); \
  } while (0)

// Phase(c): load A(c+1)->Fnext; issue corners(c+2); load desc(c+3);
// blend corners(c+1) -> Bblend; MFMA A(c) x Bmfma; barrier. Tail indices clamped.
#define PHASE(c, Fcur, Fnext, Sfill, Sblend, dvUse, dvFill, Bmfma, Bblend) do { \
    { int ca_ = (c) + 1 < 36 ? (c) + 1 : 35; LOAD_A(ca_, Fnext); } \
    { int cc2_ = (c) + 2 < 36 ? (c) + 2 : 35; CORNERS(Sfill, dvUse, cc2_); } \
    { int cc3_ = (c) + 3 < 36 ? (c) + 3 : 35; DESC_LD(cc3_, dvFill); } \
    BLEND(Sblend, Bblend); \
    MFMA4(Fcur, Bmfma); \
    BAR(); \
  } while (0)

__global__ __launch_bounds__(512, 6) void k_deform_main(
    const unsigned short* __restrict__ xt, const unsigned short* __restrict__ wp,
    const char* __restrict__ desc, float* __restrict__ out) {
  __shared__ __align__(16) char lds[8192];  // B0, B1: 4KB each
  const int t = threadIdx.x;
  const int l = t & 63;
  const int wid = t >> 6;                    // 0..7: 16-row m-slice

  // pair-preserving XCD chunked swizzle: mb 0/1 of a pair stay adjacent (same XCD)
  int orig = blockIdx.x;
  const int pid = orig >> 1;                 // 0..511
  const int mb = orig & 1;
  const int pswz = (pid & 7) * 64 + (pid >> 3);
  const int xh = pswz & 1;
  const int rowid = pswz >> 1;               // 0..255
  const int b = rowid >> 6;
  const int y = rowid & 63;

  const int p = t >> 4;                      // local position 0..31
  const int cq = t & 15;                     // channel quad (4 ch)
  const unsigned int cb8 = cq * 8;
  const int bwr = p * 128 + ((cq * 8) ^ ((p & 7) << 4));

  const int lm = l & 15;
  const int kq = (l >> 4) << 4;
  const int swz = (lm & 7) << 4;
  const int brow0 = lm * 128;
  const int brow1 = brow0 + 2048;

  f32x4 acc0 = {}, acc1 = {};

  const char* descb = desc + (size_t)(b * 36 * 4096 + y * 64 + xh * 32 + p) * 16;
  const char* xtbB = (const char*)(xt + (size_t)b * 4096 * 256);
  const unsigned short* wpl = wp + (size_t)(mb * 128 + wid * 16 + lm) * 64 + ((l >> 4) << 3);

  char* ldsB0 = lds;
  char* ldsB1 = lds + 4096;

  bf16x8 FA0, FA1, FB0, FB1;
  CSet SA, SB;
  u32x4 dvA, dvB;

  // ---- prologue: buf0 = B(0); SB = corners(1) in flight; dvA = desc(2); A(0)->FA ----
  {
    u32x4 d0, d1;
    DESC_LD(0, d0);
    DESC_LD(1, d1);
    DESC_LD(2, dvA);
    LOAD_A(0, FA);
    CSet St;
    CORNERS(St, d0, 0);
    CORNERS(SB, d1, 1);
    BLEND(St, ldsB0);
    BAR();
  }

  // ---- 36 uniform phases, 2-phase static rotation ----
  for (int pr = 0; pr < 18; ++pr) {
    const int c = pr * 2;
    PHASE(c,     FA, FB, SA, SB, dvA, dvB, ldsB0, ldsB1);   // even
    PHASE(c + 1, FB, FA, SB, SA, dvB, dvA, ldsB1, ldsB0);   // odd
  }

  // ---- epilogue: ReLU + fp32 store ----
  const int lm4 = (l >> 4) << 2;
  float* ob = out + (size_t)(b * 256 + mb * 128 + wid * 16) * 4096 + y * 64 + xh * 32;
#pragma unroll
  for (int r = 0; r < 4; ++r) {
    ob[(size_t)(lm4 + r) * 4096 + lm] = fmaxf(acc0[r], 0.f);
    ob[(size_t)(lm4 + r) * 4096 + 16 + lm] = fmaxf(acc1[r], 0.f);
  }
}

extern "C" void kernel_launch(void* const* d_in, const int* in_sizes, int n_in,
                              void* d_out, int out_size, void* d_ws, size_t ws_size,
                              hipStream_t stream) {
  const float* x     = (const float*)d_in[0];
  const float* shape = (const float*)d_in[1];
  const float* w_off = (const float*)d_in[2];
  const float* w_def = (const float*)d_in[3];
  float* out = (float*)d_out;
  char* ws = (char*)d_ws;

  char* desc          = ws;                                          // 9,437,184 B
  unsigned short* xt  = (unsigned short*)(ws + 9437184);             // 8,388,608 B
  unsigned short* wpk = (unsigned short*)(ws + 9437184 + 8388608);   // 1,179,648 B

  k_prep<<<1856, 256, 0, stream>>>(shape, w_off, x, w_def, desc, xt, wpk);
  k_deform_main<<<1024, 512, 0, stream>>>(xt, wpk, desc, out);
}

// Round 9
// 92.877 us; speedup vs baseline: 1.4042x; 1.4042x over previous
//
#include <hip/hip_runtime.h>
#include <hip/hip_bf16.h>
#include <stdint.h>

typedef __attribute__((ext_vector_type(8))) short bf16x8;
typedef __attribute__((ext_vector_type(4))) float f32x4;
typedef __attribute__((ext_vector_type(4))) unsigned int u32x4;

__device__ __forceinline__ float u2f(unsigned int u) {
  union { unsigned int i; float f; } c; c.i = u; return c.f;
}
__device__ __forceinline__ unsigned int f2b(float f) {
  union { float f; unsigned int i; } c; c.f = f;
  unsigned int x = c.i;
  return (x + 0x7fffu + ((x >> 16) & 1u)) >> 16;  // RNE to bf16
}

// ================= prep kernel =================
// blocks 0..575    : offset conv + 16B sample-descriptor build (b,g,kk) x 4 bands
// blocks 576..1599 : transpose x (B,C,H,W) f32 -> xt (B,H,W,C) bf16
// blocks 1600..1855: weight pack -> pre-swizzled rows (for linear global_load_lds staging)
__global__ __launch_bounds__(256) void k_prep(
    const float* __restrict__ shape, const float* __restrict__ w_off,
    const float* __restrict__ x, const float* __restrict__ wd,
    char* __restrict__ desc, unsigned short* __restrict__ xt,
    unsigned short* __restrict__ wp) {
  __shared__ float tile[64][65];
  int bid = blockIdx.x;
  int t = threadIdx.x;
  if (bid < 576) {
    // ---- descriptors (16B): {u32 idx01 (two u16 pos idx), u32 idx23, u32 w01, u32 w23} ----
    int band = bid & 3;
    int rem = bid >> 2;                 // = b*36 + g*9 + kk
    int b = rem / 36, r2 = rem % 36, g = r2 / 9, kk = r2 % 9;
    int ky = kk / 3, kx = kk - ky * 3;
    int ocy = g * 18 + kk * 2;
    float wy[18], wx[18];
#pragma unroll
    for (int i = 0; i < 18; ++i) { wy[i] = w_off[ocy * 18 + i]; wx[i] = w_off[(ocy + 1) * 18 + i]; }
    const float* sp = shape + (size_t)b * 2 * 4096;
    char* dp = desc + (size_t)rem * 4096 * 16;
#pragma unroll
    for (int e = 0; e < 4; ++e) {
      int p = band * 1024 + t * 4 + e;
      int y = p >> 6, xx0 = p & 63;
      float dy = 0.f, dx = 0.f;
#pragma unroll
      for (int ic = 0; ic < 2; ++ic)
#pragma unroll
        for (int kyy = 0; kyy < 3; ++kyy) {
          int yy = y + kyy - 1;
          if (yy < 0 || yy > 63) continue;
#pragma unroll
          for (int kxx = 0; kxx < 3; ++kxx) {
            int xx = xx0 + kxx - 1;
            if (xx < 0 || xx > 63) continue;
            float sv = sp[ic * 4096 + yy * 64 + xx];
            dy += sv * wy[ic * 9 + kyy * 3 + kxx];
            dx += sv * wx[ic * 9 + kyy * 3 + kxx];
          }
        }
      float sy = dy + (float)(y + ky - 1);
      float sx = dx + (float)(xx0 + kx - 1);
      float fy = floorf(sy), fx = floorf(sx);
      float ly = sy - fy, lx = sx - fx;
      int y0 = (int)fy, x0 = (int)fx;
      float vy0 = (y0 >= 0 && y0 <= 63) ? 1.f : 0.f;
      float vy1 = (y0 >= -1 && y0 <= 62) ? 1.f : 0.f;
      float vx0 = (x0 >= 0 && x0 <= 63) ? 1.f : 0.f;
      float vx1 = (x0 >= -1 && x0 <= 62) ? 1.f : 0.f;
      float w00 = (1.f - ly) * (1.f - lx) * vy0 * vx0;
      float w01 = (1.f - ly) * lx * vy0 * vx1;
      float w10 = ly * (1.f - lx) * vy1 * vx0;
      float w11 = ly * lx * vy1 * vx1;
      unsigned int yc0 = (unsigned int)min(max(y0, 0), 63);
      unsigned int yc1 = (unsigned int)min(max(y0 + 1, 0), 63);
      unsigned int xc0 = (unsigned int)min(max(x0, 0), 63);
      unsigned int xc1 = (unsigned int)min(max(x0 + 1, 0), 63);
      u32x4 d;
      d[0] = (yc0 * 64 + xc0) | ((yc0 * 64 + xc1) << 16);
      d[1] = (yc1 * 64 + xc0) | ((yc1 * 64 + xc1) << 16);
      d[2] = f2b(w00) | (f2b(w01) << 16);
      d[3] = f2b(w10) | (f2b(w11) << 16);
      *(u32x4*)(dp + (size_t)p * 16) = d;
    }
  } else if (bid < 1600) {
    // ---- transpose ----
    int id = bid - 576;
    int b = id >> 8, ct = (id >> 6) & 3, pt = id & 63;
    int c0 = ct * 64, p0 = pt * 64;
#pragma unroll
    for (int i = 0; i < 4; ++i) {
      int row = (t >> 4) + i * 16;
      int seg = t & 15;
      float4 v = *(const float4*)&x[(size_t)(b * 256 + c0 + row) * 4096 + p0 + seg * 4];
      tile[row][seg * 4 + 0] = v.x;
      tile[row][seg * 4 + 1] = v.y;
      tile[row][seg * 4 + 2] = v.z;
      tile[row][seg * 4 + 3] = v.w;
    }
    __syncthreads();
    {
      int pl = t >> 2;
      int cs = (t & 3) * 16;
      unsigned int wbuf[8];
#pragma unroll
      for (int j = 0; j < 8; ++j)
        wbuf[j] = f2b(tile[cs + 2 * j][pl]) | (f2b(tile[cs + 2 * j + 1][pl]) << 16);
      unsigned short* dst = xt + (size_t)(b * 4096 + p0 + pl) * 256 + c0 + cs;
      *(u32x4*)(dst) = *(u32x4*)&wbuf[0];
      *(u32x4*)(dst + 8) = *(u32x4*)&wbuf[4];
    }
  } else {
    // ---- weight pack (SWIZZLED): wp[chunk=kk*4+g][m][c ^ ((m&7)<<3)] = wd[m][g*64+c][kk]
    //      -> linear global_load_lds staging lands the XOR-swizzled LDS image ----
    int id = (bid - 1600) * 256 + t;
    int m = id >> 8, ci = id & 255;
    int g = ci >> 6, c = ci & 63;
    int cs = c ^ ((m & 7) << 3);
    const float* src = wd + (size_t)(m * 256 + ci) * 9;
    float v[9];
#pragma unroll
    for (int kk = 0; kk < 9; ++kk) v[kk] = src[kk];
#pragma unroll
    for (int kk = 0; kk < 9; ++kk)
      wp[(size_t)(kk * 4 + g) * 16384 + m * 64 + cs] = (unsigned short)f2b(v[kk]);
  }
}

// ================= main fused kernel =================
// grid 1024: (b, y, xq); 256 threads (4 waves) -> 4 blocks/CU, 16 waves/CU, 4 barrier groups.
// Tile M=256 x N=16 (NO sampling duplication). A: single 32KB LDS buffer staged via
// global_load_lds (pre-swizzled source). B: LDS dbuf 2x2KB. R2-schedule: corners 1 ahead,
// full drain at barrier2. 36 K-chunks of 64.
struct CSet { uint2 v0, v1, v2, v3; unsigned int w01, w23; };

#define DESC_LD(c, dv) do { \
    dv = *(const u32x4*)(descb + (size_t)(((c) & 3) * 9 + ((c) >> 2)) * 65536); \
  } while (0)

#define CORNERS(S, dv, cc) do { \
    unsigned int base_ = (unsigned int)(((cc) & 3) << 7) + cb8; \
    (S).v0 = *(const uint2*)(xtbB + (((dv)[0] & 0xffffu) << 9) + base_); \
    (S).v1 = *(const uint2*)(xtbB + (((dv)[0] >> 16) << 9) + base_); \
    (S).v2 = *(const uint2*)(xtbB + (((dv)[1] & 0xffffu) << 9) + base_); \
    (S).v3 = *(const uint2*)(xtbB + (((dv)[1] >> 16) << 9) + base_); \
    (S).w01 = (dv)[2]; \
    (S).w23 = (dv)[3]; \
  } while (0)

#define BLEND(S, bbuf) do { \
    float w0_ = u2f((S).w01 << 16), w1_ = u2f((S).w01 & 0xffff0000u); \
    float w2_ = u2f((S).w23 << 16), w3_ = u2f((S).w23 & 0xffff0000u); \
    uint2 o_; \
    { \
      float lo_ = w0_ * u2f((S).v0.x << 16) + w1_ * u2f((S).v1.x << 16) \
                + w2_ * u2f((S).v2.x << 16) + w3_ * u2f((S).v3.x << 16); \
      float hi_ = w0_ * u2f((S).v0.x & 0xffff0000u) + w1_ * u2f((S).v1.x & 0xffff0000u) \
                + w2_ * u2f((S).v2.x & 0xffff0000u) + w3_ * u2f((S).v3.x & 0xffff0000u); \
      o_.x = f2b(lo_) | (f2b(hi_) << 16); \
    } \
    { \
      float lo_ = w0_ * u2f((S).v0.y << 16) + w1_ * u2f((S).v1.y << 16) \
                + w2_ * u2f((S).v2.y << 16) + w3_ * u2f((S).v3.y << 16); \
      float hi_ = w0_ * u2f((S).v0.y & 0xffff0000u) + w1_ * u2f((S).v1.y & 0xffff0000u) \
                + w2_ * u2f((S).v2.y & 0xffff0000u) + w3_ * u2f((S).v3.y & 0xffff0000u); \
      o_.y = f2b(lo_) | (f2b(hi_) << 16); \
    } \
    *(uint2*)((bbuf) + bwr) = o_; \
  } while (0)

// stage A chunk (32KB): 256 thr x 8 x 16B linear copy of pre-swizzled image
#define STAGE_A(c) do { \
    const unsigned short* asrc_ = wp + (size_t)(c) * 16384 + t * 8; \
    _Pragma("unroll") for (int i_ = 0; i_ < 8; ++i_) \
      __builtin_amdgcn_global_load_lds( \
          (const __attribute__((address_space(1))) unsigned int*)(asrc_ + i_ * 2048), \
          (__attribute__((address_space(3))) unsigned int*)(ldsA + t * 16 + i_ * 4096), \
          16, 0, 0); \
  } while (0)

// MFMA: wave tile 64x16, A from LDS (swizzled rows), B from LDS dbuf
#define MFMA8(Bcur) do { \
    _Pragma("unroll") for (int ks_ = 0; ks_ < 2; ++ks_) { \
      const int kb_ = ks_ * 64 + kq16; \
      bf16x8 bf_ = *(const bf16x8*)((Bcur) + lm * 128 + (kb_ ^ swz)); \
      bf16x8 a0_ = *(const bf16x8*)(ldsA + (wbase + lm) * 128 + (kb_ ^ swz)); \
      bf16x8 a1_ = *(const bf16x8*)(ldsA + (wbase + 16 + lm) * 128 + (kb_ ^ swz)); \
      bf16x8 a2_ = *(const bf16x8*)(ldsA + (wbase + 32 + lm) * 128 + (kb_ ^ swz)); \
      bf16x8 a3_ = *(const bf16x8*)(ldsA + (wbase + 48 + lm) * 128 + (kb_ ^ swz)); \
      acc0 = __builtin_amdgcn_mfma_f32_16x16x32_bf16(a0_, bf_, acc0, 0, 0, 0); \
      acc1 = __builtin_amdgcn_mfma_f32_16x16x32_bf16(a1_, bf_, acc1, 0, 0, 0); \
      acc2 = __builtin_amdgcn_mfma_f32_16x16x32_bf16(a2_, bf_, acc2, 0, 0, 0); \
      acc3 = __builtin_amdgcn_mfma_f32_16x16x32_bf16(a3_, bf_, acc3, 0, 0, 0); \
    } \
  } while (0)

#define BAR_LGKM() do { \
    asm volatile("s_waitcnt lgkmcnt(0)" ::: "memory"); \
    __builtin_amdgcn_s_barrier(); \
  } while (0)

#define BAR_FULL() do { \
    asm volatile("s_waitcnt vmcnt(0) lgkmcnt(0)" ::: "memory"); \
    __builtin_amdgcn_s_barrier(); \
  } while (0)

// Phase(c) [enter: A(c) staged, B(c) in Bcur, S = corners(c+1) arrived, dvU = desc(c+2)]:
// blend->Bnext; MFMA(c); bar1 (A reads done); corners(c+2); desc(c+3); stage A(c+1);
// bar2 (drain all). Tail indices clamped (harmless re-reads).
#define PHASE(c, S, dvU, dvF, Bcur, Bnext) do { \
    BLEND(S, Bnext); \
    MFMA8(Bcur); \
    BAR_LGKM(); \
    { int cc_ = (c) + 2 < 36 ? (c) + 2 : 35; CORNERS(S, dvU, cc_); } \
    { int cd_ = (c) + 3 < 36 ? (c) + 3 : 35; DESC_LD(cd_, dvF); } \
    { int ca_ = (c) + 1 < 36 ? (c) + 1 : 35; STAGE_A(ca_); } \
    BAR_FULL(); \
  } while (0)

__global__ __launch_bounds__(256, 4) void k_deform_main(
    const unsigned short* __restrict__ xt, const unsigned short* __restrict__ wp,
    const char* __restrict__ desc, float* __restrict__ out) {
  __shared__ __align__(16) char lds[36864];  // A: 32KB single; B0,B1: 2KB each
  const int t = threadIdx.x;
  const int l = t & 63;
  const int wid = t >> 6;                    // 0..3: 64-row m-slice
  const int wbase = wid * 64;

  int orig = blockIdx.x;
  int bid = (orig & 7) * 128 + (orig >> 3);  // XCD chunked swizzle (1024%8==0)
  const int xq = bid & 3;
  const int rowid = bid >> 2;                // 0..255
  const int b = rowid >> 6;
  const int y = rowid & 63;

  const int p = t >> 4;                      // local position 0..15
  const int cq = t & 15;                     // channel quad (4 ch)
  const unsigned int cb8 = cq * 8;
  const int bwr = p * 128 + ((cq * 8) ^ ((p & 7) << 4));

  const int lm = l & 15;
  const int kq16 = (l >> 4) << 4;
  const int swz = (lm & 7) << 4;

  f32x4 acc0 = {}, acc1 = {}, acc2 = {}, acc3 = {};

  const char* descb = desc + (size_t)(b * 36 * 4096 + y * 64 + xq * 16 + p) * 16;
  const char* xtbB = (const char*)(xt + (size_t)b * 4096 * 256);

  char* ldsA = lds;
  char* ldsB0 = lds + 32768;
  char* ldsB1 = lds + 34816;

  CSet S;
  u32x4 dvA, dvB;

  // ---- prologue: B(0) built; corners(1) in flight; desc(2) held; A(0) staged; drain ----
  {
    u32x4 d0, d1;
    DESC_LD(0, d0);
    DESC_LD(1, d1);
    DESC_LD(2, dvA);
    CORNERS(S, d0, 0);
    BLEND(S, ldsB0);
    CORNERS(S, d1, 1);
    STAGE_A(0);
    BAR_FULL();
  }

  // ---- 36 phases, 2-phase B rotation, 2-slot desc rotation ----
  for (int pr = 0; pr < 18; ++pr) {
    const int c = pr * 2;
    PHASE(c,     S, dvA, dvB, ldsB0, ldsB1);
    PHASE(c + 1, S, dvB, dvA, ldsB1, ldsB0);
  }

  // ---- epilogue: ReLU + fp32 store ----
  const int lm4 = (l >> 4) << 2;
  float* ob = out + (size_t)(b * 256 + wbase) * 4096 + y * 64 + xq * 16 + lm;
#pragma unroll
  for (int r = 0; r < 4; ++r) {
    ob[(size_t)(lm4 + r) * 4096] = fmaxf(acc0[r], 0.f);
    ob[(size_t)(16 + lm4 + r) * 4096] = fmaxf(acc1[r], 0.f);
    ob[(size_t)(32 + lm4 + r) * 4096] = fmaxf(acc2[r], 0.f);
    ob[(size_t)(48 + lm4 + r) * 4096] = fmaxf(acc3[r], 0.f);
  }
}

extern "C" void kernel_launch(void* const* d_in, const int* in_sizes, int n_in,
                              void* d_out, int out_size, void* d_ws, size_t ws_size,
                              hipStream_t stream) {
  const float* x     = (const float*)d_in[0];
  const float* shape = (const float*)d_in[1];
  const float* w_off = (const float*)d_in[2];
  const float* w_def = (const float*)d_in[3];
  float* out = (float*)d_out;
  char* ws = (char*)d_ws;

  char* desc          = ws;                                          // 9,437,184 B
  unsigned short* xt  = (unsigned short*)(ws + 9437184);             // 8,388,608 B
  unsigned short* wpk = (unsigned short*)(ws + 9437184 + 8388608);   // 1,179,648 B

  k_prep<<<1856, 256, 0, stream>>>(shape, w_off, x, w_def, desc, xt, wpk);
  k_deform_main<<<1024, 256, 0, stream>>>(xt, wpk, desc, out);
}

// Round 10
// 69.944 us; speedup vs baseline: 1.8646x; 1.3279x over previous
//
#include <hip/hip_runtime.h>
#include <hip/hip_bf16.h>
#include <stdint.h>

typedef __attribute__((ext_vector_type(8))) short bf16x8;
typedef __attribute__((ext_vector_type(4))) float f32x4;
typedef __attribute__((ext_vector_type(4))) unsigned int u32x4;

__device__ __forceinline__ float u2f(unsigned int u) {
  union { unsigned int i; float f; } c; c.i = u; return c.f;
}
__device__ __forceinline__ unsigned int f2b(float f) {
  union { float f; unsigned int i; } c; c.f = f;
  unsigned int x = c.i;
  return (x + 0x7fffu + ((x >> 16) & 1u)) >> 16;  // RNE to bf16
}

// ================= prep kernel (= R9) =================
__global__ __launch_bounds__(256) void k_prep(
    const float* __restrict__ shape, const float* __restrict__ w_off,
    const float* __restrict__ x, const float* __restrict__ wd,
    char* __restrict__ desc, unsigned short* __restrict__ xt,
    unsigned short* __restrict__ wp) {
  __shared__ float tile[64][65];
  int bid = blockIdx.x;
  int t = threadIdx.x;
  if (bid < 576) {
    // ---- descriptors (16B): {u32 idx01 (two u16 pos idx), u32 idx23, u32 w01, u32 w23} ----
    int band = bid & 3;
    int rem = bid >> 2;                 // = b*36 + g*9 + kk
    int b = rem / 36, r2 = rem % 36, g = r2 / 9, kk = r2 % 9;
    int ky = kk / 3, kx = kk - ky * 3;
    int ocy = g * 18 + kk * 2;
    float wy[18], wx[18];
#pragma unroll
    for (int i = 0; i < 18; ++i) { wy[i] = w_off[ocy * 18 + i]; wx[i] = w_off[(ocy + 1) * 18 + i]; }
    const float* sp = shape + (size_t)b * 2 * 4096;
    char* dp = desc + (size_t)rem * 4096 * 16;
#pragma unroll
    for (int e = 0; e < 4; ++e) {
      int p = band * 1024 + t * 4 + e;
      int y = p >> 6, xx0 = p & 63;
      float dy = 0.f, dx = 0.f;
#pragma unroll
      for (int ic = 0; ic < 2; ++ic)
#pragma unroll
        for (int kyy = 0; kyy < 3; ++kyy) {
          int yy = y + kyy - 1;
          if (yy < 0 || yy > 63) continue;
#pragma unroll
          for (int kxx = 0; kxx < 3; ++kxx) {
            int xx = xx0 + kxx - 1;
            if (xx < 0 || xx > 63) continue;
            float sv = sp[ic * 4096 + yy * 64 + xx];
            dy += sv * wy[ic * 9 + kyy * 3 + kxx];
            dx += sv * wx[ic * 9 + kyy * 3 + kxx];
          }
        }
      float sy = dy + (float)(y + ky - 1);
      float sx = dx + (float)(xx0 + kx - 1);
      float fy = floorf(sy), fx = floorf(sx);
      float ly = sy - fy, lx = sx - fx;
      int y0 = (int)fy, x0 = (int)fx;
      float vy0 = (y0 >= 0 && y0 <= 63) ? 1.f : 0.f;
      float vy1 = (y0 >= -1 && y0 <= 62) ? 1.f : 0.f;
      float vx0 = (x0 >= 0 && x0 <= 63) ? 1.f : 0.f;
      float vx1 = (x0 >= -1 && x0 <= 62) ? 1.f : 0.f;
      float w00 = (1.f - ly) * (1.f - lx) * vy0 * vx0;
      float w01 = (1.f - ly) * lx * vy0 * vx1;
      float w10 = ly * (1.f - lx) * vy1 * vx0;
      float w11 = ly * lx * vy1 * vx1;
      unsigned int yc0 = (unsigned int)min(max(y0, 0), 63);
      unsigned int yc1 = (unsigned int)min(max(y0 + 1, 0), 63);
      unsigned int xc0 = (unsigned int)min(max(x0, 0), 63);
      unsigned int xc1 = (unsigned int)min(max(x0 + 1, 0), 63);
      u32x4 d;
      d[0] = (yc0 * 64 + xc0) | ((yc0 * 64 + xc1) << 16);
      d[1] = (yc1 * 64 + xc0) | ((yc1 * 64 + xc1) << 16);
      d[2] = f2b(w00) | (f2b(w01) << 16);
      d[3] = f2b(w10) | (f2b(w11) << 16);
      *(u32x4*)(dp + (size_t)p * 16) = d;
    }
  } else if (bid < 1600) {
    // ---- transpose ----
    int id = bid - 576;
    int b = id >> 8, ct = (id >> 6) & 3, pt = id & 63;
    int c0 = ct * 64, p0 = pt * 64;
#pragma unroll
    for (int i = 0; i < 4; ++i) {
      int row = (t >> 4) + i * 16;
      int seg = t & 15;
      float4 v = *(const float4*)&x[(size_t)(b * 256 + c0 + row) * 4096 + p0 + seg * 4];
      tile[row][seg * 4 + 0] = v.x;
      tile[row][seg * 4 + 1] = v.y;
      tile[row][seg * 4 + 2] = v.z;
      tile[row][seg * 4 + 3] = v.w;
    }
    __syncthreads();
    {
      int pl = t >> 2;
      int cs = (t & 3) * 16;
      unsigned int wbuf[8];
#pragma unroll
      for (int j = 0; j < 8; ++j)
        wbuf[j] = f2b(tile[cs + 2 * j][pl]) | (f2b(tile[cs + 2 * j + 1][pl]) << 16);
      unsigned short* dst = xt + (size_t)(b * 4096 + p0 + pl) * 256 + c0 + cs;
      *(u32x4*)(dst) = *(u32x4*)&wbuf[0];
      *(u32x4*)(dst + 8) = *(u32x4*)&wbuf[4];
    }
  } else {
    // ---- weight pack (SWIZZLED for linear global_load_lds staging) ----
    int id = (bid - 1600) * 256 + t;
    int m = id >> 8, ci = id & 255;
    int g = ci >> 6, c = ci & 63;
    int cs = c ^ ((m & 7) << 3);
    const float* src = wd + (size_t)(m * 256 + ci) * 9;
    float v[9];
#pragma unroll
    for (int kk = 0; kk < 9; ++kk) v[kk] = src[kk];
#pragma unroll
    for (int kk = 0; kk < 9; ++kk)
      wp[(size_t)(kk * 4 + g) * 16384 + m * 64 + cs] = (unsigned short)f2b(v[kk]);
  }
}

// ================= main fused kernel =================
// R3 structure + counted-vmcnt barrier. grid 512: (b,y,xh); 512 thr (8 waves);
// tile M=256 x N=32; A: LDS dbuf 2x32KB via global_load_lds (pre-swizzled);
// B: LDS dbuf 2x4KB. ONE barrier per phase: lgkmcnt(0)+vmcnt(5)+s_barrier —
// drains the 4 stage loads only; 4 corners + 1 desc fly across the barrier.
struct CSet { uint2 v0, v1, v2, v3; unsigned int w01, w23; };

#define DESC_LD(c, dv) do { \
    dv = *(const u32x4*)(descb + (size_t)(((c) & 3) * 9 + ((c) >> 2)) * 65536); \
  } while (0)

#define CORNERS(S, dv, cc) do { \
    unsigned int base_ = (unsigned int)(((cc) & 3) << 7) + cb8; \
    (S).v0 = *(const uint2*)(xtbB + (((dv)[0] & 0xffffu) << 9) + base_); \
    (S).v1 = *(const uint2*)(xtbB + (((dv)[0] >> 16) << 9) + base_); \
    (S).v2 = *(const uint2*)(xtbB + (((dv)[1] & 0xffffu) << 9) + base_); \
    (S).v3 = *(const uint2*)(xtbB + (((dv)[1] >> 16) << 9) + base_); \
    (S).w01 = (dv)[2]; \
    (S).w23 = (dv)[3]; \
  } while (0)

#define BLEND(S, bbuf) do { \
    float w0_ = u2f((S).w01 << 16), w1_ = u2f((S).w01 & 0xffff0000u); \
    float w2_ = u2f((S).w23 << 16), w3_ = u2f((S).w23 & 0xffff0000u); \
    uint2 o_; \
    { \
      float lo_ = w0_ * u2f((S).v0.x << 16) + w1_ * u2f((S).v1.x << 16) \
                + w2_ * u2f((S).v2.x << 16) + w3_ * u2f((S).v3.x << 16); \
      float hi_ = w0_ * u2f((S).v0.x & 0xffff0000u) + w1_ * u2f((S).v1.x & 0xffff0000u) \
                + w2_ * u2f((S).v2.x & 0xffff0000u) + w3_ * u2f((S).v3.x & 0xffff0000u); \
      o_.x = f2b(lo_) | (f2b(hi_) << 16); \
    } \
    { \
      float lo_ = w0_ * u2f((S).v0.y << 16) + w1_ * u2f((S).v1.y << 16) \
                + w2_ * u2f((S).v2.y << 16) + w3_ * u2f((S).v3.y << 16); \
      float hi_ = w0_ * u2f((S).v0.y & 0xffff0000u) + w1_ * u2f((S).v1.y & 0xffff0000u) \
                + w2_ * u2f((S).v2.y & 0xffff0000u) + w3_ * u2f((S).v3.y & 0xffff0000u); \
      o_.y = f2b(lo_) | (f2b(hi_) << 16); \
    } \
    *(uint2*)((bbuf) + bwr) = o_; \
  } while (0)

// stage A chunk (32KB): 512 thr x 4 x 16B linear copy of pre-swizzled image
#define STAGE_A(c, abuf) do { \
    const unsigned short* asrc_ = wp + (size_t)(c) * 16384 + t * 8; \
    _Pragma("unroll") for (int i_ = 0; i_ < 4; ++i_) \
      __builtin_amdgcn_global_load_lds( \
          (const __attribute__((address_space(1))) unsigned int*)(asrc_ + i_ * 4096), \
          (__attribute__((address_space(3))) unsigned int*)((abuf) + t * 16 + i_ * 8192), \
          16, 0, 0); \
  } while (0)

#define MFMA_STEP(abuf, bbuf) do { \
    _Pragma("unroll") for (int ks_ = 0; ks_ < 2; ++ks_) { \
      int kb_ = ks_ * 64 + kq; \
      bf16x8 a0_ = *(const bf16x8*)((abuf) + (wid * 32 + lm) * 128 + (kb_ ^ swz)); \
      bf16x8 a1_ = *(const bf16x8*)((abuf) + (wid * 32 + 16 + lm) * 128 + (kb_ ^ swz)); \
      bf16x8 b0_ = *(const bf16x8*)((bbuf) + lm * 128 + (kb_ ^ swz)); \
      bf16x8 b1_ = *(const bf16x8*)((bbuf) + (16 + lm) * 128 + (kb_ ^ swz)); \
      acc00 = __builtin_amdgcn_mfma_f32_16x16x32_bf16(a0_, b0_, acc00, 0, 0, 0); \
      acc01 = __builtin_amdgcn_mfma_f32_16x16x32_bf16(a0_, b1_, acc01, 0, 0, 0); \
      acc10 = __builtin_amdgcn_mfma_f32_16x16x32_bf16(a1_, b0_, acc10, 0, 0, 0); \
      acc11 = __builtin_amdgcn_mfma_f32_16x16x32_bf16(a1_, b1_, acc11, 0, 0, 0); \
    } \
  } while (0)

// Phase(c): stage A(c+1)->other A buf; issue corners(c+2); load desc(c+3);
// MFMA A(c)xB(c); blend corners(c+1)->B(c+1); lgkm(0)+vmcnt(5)+barrier.
#define PHASE(c, Acur, Anext, Bcur, Bnext, Sfill, Sblend, dvUse, dvFill) do { \
    { int ca_ = (c) + 1 < 36 ? (c) + 1 : 35; STAGE_A(ca_, Anext); } \
    { int cc_ = (c) + 2 < 36 ? (c) + 2 : 35; CORNERS(Sfill, dvUse, cc_); } \
    { int cd_ = (c) + 3 < 36 ? (c) + 3 : 35; DESC_LD(cd_, dvFill); } \
    MFMA_STEP(Acur, Bcur); \
    BLEND(Sblend, Bnext); \
    asm volatile("s_waitcnt lgkmcnt(0)" ::: "memory"); \
    asm volatile("s_waitcnt vmcnt(5)" ::: "memory"); \
    __builtin_amdgcn_s_barrier(); \
  } while (0)

__global__ __launch_bounds__(512, 4) void k_deform_main(
    const unsigned short* __restrict__ xt, const unsigned short* __restrict__ wp,
    const char* __restrict__ desc, float* __restrict__ out) {
  __shared__ __align__(16) char lds[73728];  // A0,A1: 32KB; B0,B1: 4KB
  const int t = threadIdx.x;
  const int l = t & 63;
  const int wid = t >> 6;                    // 0..7 (32-row m-slice)

  int orig = blockIdx.x;
  int bid = (orig & 7) * 64 + (orig >> 3);   // XCD chunked swizzle (512%8==0)
  const int xh = bid & 1;
  const int rowid = bid >> 1;
  const int b = rowid >> 6;
  const int y = rowid & 63;

  const int p = t >> 4;              // local position 0..31
  const int cq = t & 15;             // channel quad (4 ch)
  const unsigned int cb8 = cq * 8;
  const int bwr = p * 128 + ((cq * 8) ^ ((p & 7) << 4));

  const int lm = l & 15;
  const int kq = (l >> 4) << 4;
  const int swz = (lm & 7) << 4;

  f32x4 acc00 = {}, acc01 = {}, acc10 = {}, acc11 = {};

  const char* descb = desc + (size_t)(b * 36 * 4096 + y * 64 + xh * 32 + p) * 16;
  const char* xtbB = (const char*)(xt + (size_t)b * 4096 * 256);

  char* ldsA0 = lds;
  char* ldsA1 = lds + 32768;
  char* ldsB0 = lds + 65536;
  char* ldsB1 = lds + 69632;

  CSet SE, SO;
  u32x4 dvA, dvB;

  // ---- prologue: A(0) staged+drained; B(0) built; SO=corners(1) flying; dvA=desc(2) ----
  {
    u32x4 d0, d1;
    DESC_LD(0, d0);
    DESC_LD(1, d1);
    DESC_LD(2, dvA);
    STAGE_A(0, ldsA0);
    CSet St;
    CORNERS(St, d0, 0);
    BLEND(St, ldsB0);                 // waits on St corners
    CORNERS(SO, d1, 1);               // stays in flight
    asm volatile("s_waitcnt lgkmcnt(0)" ::: "memory");
    asm volatile("s_waitcnt vmcnt(4)" ::: "memory");   // drain stage(0)+desc; keep SO
    __builtin_amdgcn_s_barrier();
  }

  // ---- 36 phases, 2-phase rotation ----
  for (int pr = 0; pr < 18; ++pr) {
    const int c = pr * 2;
    PHASE(c,     ldsA0, ldsA1, ldsB0, ldsB1, SE, SO, dvA, dvB);
    PHASE(c + 1, ldsA1, ldsA0, ldsB1, ldsB0, SO, SE, dvB, dvA);
  }

  // ---- epilogue: ReLU + fp32 store ----
  const int lm4 = (l >> 4) << 2;
  float* ob = out + (size_t)(b * 256 + wid * 32) * 4096 + y * 64 + xh * 32;
#pragma unroll
  for (int r = 0; r < 4; ++r) {
    ob[(size_t)(lm4 + r) * 4096 + lm] = fmaxf(acc00[r], 0.f);
    ob[(size_t)(lm4 + r) * 4096 + 16 + lm] = fmaxf(acc01[r], 0.f);
    ob[(size_t)(16 + lm4 + r) * 4096 + lm] = fmaxf(acc10[r], 0.f);
    ob[(size_t)(16 + lm4 + r) * 4096 + 16 + lm] = fmaxf(acc11[r], 0.f);
  }
}

extern "C" void kernel_launch(void* const* d_in, const int* in_sizes, int n_in,
                              void* d_out, int out_size, void* d_ws, size_t ws_size,
                              hipStream_t stream) {
  const float* x     = (const float*)d_in[0];
  const float* shape = (const float*)d_in[1];
  const float* w_off = (const float*)d_in[2];
  const float* w_def = (const float*)d_in[3];
  float* out = (float*)d_out;
  char* ws = (char*)d_ws;

  char* desc          = ws;                                          // 9,437,184 B
  unsigned short* xt  = (unsigned short*)(ws + 9437184);             // 8,388,608 B
  unsigned short* wpk = (unsigned short*)(ws + 9437184 + 8388608);   // 1,179,648 B

  k_prep<<<1856, 256, 0, stream>>>(shape, w_off, x, w_def, desc, xt, wpk);
  k_deform_main<<<512, 512, 0, stream>>>(xt, wpk, desc, out);
}